// Round 16
// baseline (142.537 us; speedup 1.0000x reference)
//
#include <hip/hip_runtime.h>
#include <math.h>

#define BB 4
#define SS 2048
#define DD 1024
#define NHD 8
#define DHD 128
#define NC 16
#define CL 128
#define SCALE 0.08838834764831845f

// workspace offsets (in floats)
#define OFF_IG   0
#define OFF_LF   65536
#define OFF_B    131072
#define OFF_G    196608
#define OFF_E    262144
#define OFF_RM   327680
#define OFF_MIN  393216
#define OFF_SC   393728
#define OFF_UN   396288
#define OFF_NIN  461824
#define OFF_U    527360      // f16: WT (gates) then U^T/Cin^T
#define OFF_KH   4721664     // f16 mirror of k
#define OFF_VT   8915968     // f16 V^T per (bh,g)
#define OFF_IG2  13110272    // gates K-half-1 partial (raw)
#define OFF_LF2  13175808    // gates K-half-1 partial (raw)
// out offsets (floats)
#define OUT_C  8388608
#define OUT_N  8912896
#define OUT_M  8916992

typedef __attribute__((ext_vector_type(8))) _Float16 f16x8;
typedef __attribute__((ext_vector_type(4))) float f32x4;

__device__ __forceinline__ unsigned pk2h(float a, float b) {
  union { _Float16 h[2]; unsigned u; } f;
  f.h[0] = (_Float16)a; f.h[1] = (_Float16)b;
  return f.u;
}
__device__ __forceinline__ f16x8 mkfrag(float4 a, float4 c) {
  f16x8 f;
  f[0] = (_Float16)a.x; f[1] = (_Float16)a.y; f[2] = (_Float16)a.z; f[3] = (_Float16)a.w;
  f[4] = (_Float16)c.x; f[5] = (_Float16)c.y; f[6] = (_Float16)c.z; f[7] = (_Float16)c.w;
  return f;
}
// 256B rows, XOR-swizzle byte bits 4..6 with row&7
__device__ __forceinline__ char* swp(char* base, int row, int byte) {
  return base + (((row << 8) + byte) ^ ((row & 7) << 4));
}

// ---------------------------------------------------------------------------
// Kernel 0: transpose Wi|Wf -> WT f16 [16][3072] (validated).
// ---------------------------------------------------------------------------
__global__ __launch_bounds__(256) void wtrans_kernel(const float* __restrict__ Wi,
                                                     const float* __restrict__ Wf,
                                                     _Float16* __restrict__ WT) {
  const int kk = blockIdx.x * 256 + threadIdx.x;   // 0..3071
  float4 wa = *(const float4*)(Wi + (size_t)kk * 8);
  float4 wb = *(const float4*)(Wi + (size_t)kk * 8 + 4);
  float4 fa = *(const float4*)(Wf + (size_t)kk * 8);
  float4 fb = *(const float4*)(Wf + (size_t)kk * 8 + 4);
  WT[0 * 3072 + kk]  = (_Float16)wa.x; WT[1 * 3072 + kk]  = (_Float16)wa.y;
  WT[2 * 3072 + kk]  = (_Float16)wa.z; WT[3 * 3072 + kk]  = (_Float16)wa.w;
  WT[4 * 3072 + kk]  = (_Float16)wb.x; WT[5 * 3072 + kk]  = (_Float16)wb.y;
  WT[6 * 3072 + kk]  = (_Float16)wb.z; WT[7 * 3072 + kk]  = (_Float16)wb.w;
  WT[8 * 3072 + kk]  = (_Float16)fa.x; WT[9 * 3072 + kk]  = (_Float16)fa.y;
  WT[10 * 3072 + kk] = (_Float16)fa.z; WT[11 * 3072 + kk] = (_Float16)fa.w;
  WT[12 * 3072 + kk] = (_Float16)fb.x; WT[13 * 3072 + kk] = (_Float16)fb.y;
  WT[14 * 3072 + kk] = (_Float16)fb.z; WT[15 * 3072 + kk] = (_Float16)fb.w;
}

// ---------------------------------------------------------------------------
// Kernel 1 (v5): gates MFMA, K-SPLIT over 2 blocks (validated r15).
// ---------------------------------------------------------------------------
__global__ __launch_bounds__(512) void gates_kernel(
    const float* __restrict__ q, const float* __restrict__ k, const float* __restrict__ v,
    const _Float16* __restrict__ WT, float* __restrict__ ws,
    _Float16* __restrict__ kh) {
  __shared__ float red[8][256];
  const int tid = threadIdx.x, wid = tid >> 6, lane = tid & 63;
  const int g16 = lane >> 4, l15 = lane & 15;
  const int khalf = blockIdx.x & 1;
  const int rb = blockIdx.x >> 1;
  const int g0 = rb * 16;
  const int b = g0 >> 11, t0 = g0 & (SS - 1);

  const size_t rowoff = (size_t)b * SS * DD + (size_t)(t0 + l15) * DD;
  const float* qr = q + rowoff;
  const float* kr = k + rowoff;
  const float* vr = v + rowoff;

  f32x4 acc = {0.f, 0.f, 0.f, 0.f};
  const int ks0 = khalf * 48 + wid * 6;
  #pragma unroll
  for (int grp = 0; grp < 3; ++grp) {
    const int s0 = ks0 + grp * 2;
    const int seg = s0 >> 5;
    const float* base = (seg == 0) ? qr : (seg == 1) ? kr : vr;
    const float* Ab = base + (s0 & 31) * 32 + g16 * 8;
    const _Float16* Bb = WT + l15 * 3072 + s0 * 32 + g16 * 8;
    float4 a[2], c[2]; f16x8 bfr[2];
    #pragma unroll
    for (int j = 0; j < 2; ++j) {
      a[j]   = *(const float4*)(Ab + j * 32);
      c[j]   = *(const float4*)(Ab + j * 32 + 4);
      bfr[j] = *(const f16x8*)(Bb + j * 32);
    }
    if (seg == 1) {
      const int coff = (s0 & 31) * 32 + g16 * 8;
      #pragma unroll
      for (int j = 0; j < 2; ++j)
        *(f16x8*)(kh + rowoff + coff + j * 32) = mkfrag(a[j], c[j]);
    }
    #pragma unroll
    for (int j = 0; j < 2; ++j)
      acc = __builtin_amdgcn_mfma_f32_16x16x32_f16(mkfrag(a[j], c[j]), bfr[j], acc, 0, 0, 0);
  }
  #pragma unroll
  for (int r = 0; r < 4; ++r) red[wid][(g16 * 4 + r) * 16 + l15] = acc[r];
  __syncthreads();

  if (tid < 256) {
    float s = 0.f;
    #pragma unroll
    for (int w = 0; w < 8; ++w) s += red[w][tid];
    const int row = tid >> 4, gate = tid & 15;
    const int t = t0 + row;
    float* igb = ws + (khalf ? OFF_IG2 : OFF_IG);
    float* lfb = ws + (khalf ? OFF_LF2 : OFF_LF);
    if (gate < 8) igb[(size_t)(b * NHD + gate) * SS + t] = s;
    else          lfb[(size_t)(b * NHD + gate - 8) * SS + t] = s;
  }
}

// ---------------------------------------------------------------------------
// Kernel 2a: per-chunk scans + gate partial sum + bias/lsig (validated r15).
// ---------------------------------------------------------------------------
__global__ __launch_bounds__(128) void prep1_kernel(float* __restrict__ ws,
                                                    const float* __restrict__ bi,
                                                    const float* __restrict__ bfb) {
  const int g  = blockIdx.x & 15;
  const int bh = blockIdx.x >> 4;
  const int hh = bh & 7;
  const int s  = threadIdx.x;
  __shared__ float sh[128];
  __shared__ float bc1;
  const int t = g * CL + s;
  const size_t off = (size_t)bh * SS + t;
  float ft  = ws[OFF_LF + off] + ws[OFF_LF2 + off] + bfb[hh];
  float lfv = fminf(ft, 0.f) - log1pf(expf(-fabsf(ft)));
  float iv  = ws[OFF_IG + off] + ws[OFF_IG2 + off] + bi[hh];
  float v = lfv;
  sh[s] = v; __syncthreads();
  for (int off2 = 1; off2 < 128; off2 <<= 1) {
    float tv = (s >= off2) ? sh[s - off2] : 0.f;
    __syncthreads();
    v += tv; sh[s] = v; __syncthreads();
  }
  float Bv = v;
  float Gv = iv - Bv;
  v = Gv; sh[s] = v; __syncthreads();
  for (int off2 = 1; off2 < 128; off2 <<= 1) {
    float tv = (s >= off2) ? sh[s - off2] : -3.0e38f;
    __syncthreads();
    v = fmaxf(v, tv); sh[s] = v; __syncthreads();
  }
  float Rv = v;
  if (s == 127) bc1 = Rv;
  __syncthreads();
  float mxG = bc1;
  ws[OFF_B  + off] = Bv;
  ws[OFF_G  + off] = Gv;
  ws[OFF_RM + off] = Rv;
  ws[OFF_E  + off] = expf(Gv - mxG);
}

// Kernel 2b: per-bh cross-chunk scalar chain (validated r9/r15).
__global__ __launch_bounds__(64) void prep2_kernel(float* __restrict__ ws,
                                                   const float* __restrict__ m0,
                                                   float* __restrict__ out) {
  const int bh = blockIdx.x;
  if (threadIdx.x != 0) return;
  const float m0v = m0[bh];
  float m_run = m0v, LFtot = 0.f;
  float mina[NC], mxga[NC], lfsa[NC];
  #pragma unroll
  for (int g = 0; g < NC; ++g) {
    float Bend = ws[OFF_B  + (size_t)bh * SS + g * CL + 127];
    float mxG  = ws[OFF_RM + (size_t)bh * SS + g * CL + 127];
    ws[OFF_MIN + bh * NC + g] = m_run;
    mina[g] = m_run; mxga[g] = mxG; lfsa[g] = LFtot;
    m_run = Bend + fmaxf(m_run, mxG);
    LFtot += Bend;
  }
  out[OUT_M + bh] = m_run;
  float* sc = ws + OFF_SC + bh * 80;
  float S = -3.0e38f;
  #pragma unroll
  for (int g = 0; g < NC; ++g) {
    float r_g = lfsa[g] - mina[g];
    sc[g]      = expf(S + r_g);
    sc[20 + g] = expf(m0v + lfsa[g] - mina[g]);
    float s_g = mxga[g] - lfsa[g];
    float Sn = fmaxf(S, s_g);
    sc[40 + g] = expf(S - Sn);
    sc[60 + g] = expf(s_g - Sn);
    S = Sn;
  }
  sc[16] = expf(S + LFtot - m_run);
  sc[36] = expf(m0v + LFtot - m_run);
}

// ---------------------------------------------------------------------------
// Kernel 3 (v2): MFMA U^T + Un + V^T dump, 512 thr / 8 waves (validated r15).
// ---------------------------------------------------------------------------
__global__ __launch_bounds__(512) void u_kernel(const float* __restrict__ k,
                                                const float* __restrict__ v,
                                                float* __restrict__ ws) {
  extern __shared__ char smem[];
  char* Kt = smem;
  char* Vt = smem + 32768;

  const int tid = threadIdx.x;
  const int wid = tid >> 6;          // 0..7
  const int lane = tid & 63;
  const int g16 = lane >> 4;
  const int l15 = lane & 15;
  const int g  = blockIdx.x & 15;
  const int bh = blockIdx.x >> 4;
  const int b = bh >> 3, hh = bh & 7;
  const size_t headoff = (size_t)b * SS * DD + (size_t)hh * SS * DHD;
  const float* kb = k + headoff + (size_t)g * CL * DHD;
  const float* vb = v + headoff + (size_t)g * CL * DHD;
  const float* E  = ws + OFF_E + (size_t)bh * SS + g * CL;

  #pragma unroll 4
  for (int it = 0; it < 8; ++it) {
    const int idx = (it << 9) + tid;
    const int c  = idx & 127;
    const int r0 = (idx >> 7) << 2;
    float e0 = E[r0] * SCALE, e1 = E[r0 + 1] * SCALE,
          e2 = E[r0 + 2] * SCALE, e3 = E[r0 + 3] * SCALE;
    float a0 = kb[(size_t)r0 * DHD + c] * e0;
    float a1 = kb[(size_t)(r0 + 1) * DHD + c] * e1;
    float a2 = kb[(size_t)(r0 + 2) * DHD + c] * e2;
    float a3 = kb[(size_t)(r0 + 3) * DHD + c] * e3;
    *(uint2*)swp(Kt, c, r0 * 2) = make_uint2(pk2h(a0, a1), pk2h(a2, a3));
    float b0 = vb[(size_t)r0 * DHD + c];
    float b1 = vb[(size_t)(r0 + 1) * DHD + c];
    float b2 = vb[(size_t)(r0 + 2) * DHD + c];
    float b3 = vb[(size_t)(r0 + 3) * DHD + c];
    *(uint2*)swp(Vt, c, r0 * 2) = make_uint2(pk2h(b0, b1), pk2h(b2, b3));
  }
  __syncthreads();

  _Float16* VTg = (_Float16*)(ws + OFF_VT) + (size_t)(bh * NC + g) * 16384;
  #pragma unroll
  for (int it2 = 0; it2 < 4; ++it2) {
    const int ci = (it2 << 9) + tid;
    const int j = ci >> 4, rp = ci & 15;
    f16x8 x = *(f16x8*)swp(Vt, j, rp * 16);
    *(f16x8*)(VTg + j * 128 + rp * 8) = x;
  }

  if (tid < 128) {
    float s = 0.f;
    #pragma unroll
    for (int r8 = 0; r8 < 16; ++r8) {
      f16x8 x = *(f16x8*)swp(Kt, tid, r8 * 16);
      s += (float)x[0] + (float)x[1] + (float)x[2] + (float)x[3]
         + (float)x[4] + (float)x[5] + (float)x[6] + (float)x[7];
    }
    ws[OFF_UN + (size_t)(bh * NC + g) * DHD + tid] = s;
  }

  _Float16* UTb = (_Float16*)(ws + OFF_U) + (size_t)(bh * NC + g) * 16384;
  const int it0 = wid;
  #pragma unroll 1
  for (int jt = 0; jt < 8; ++jt) {
    f32x4 a0 = {0.f, 0.f, 0.f, 0.f};
    #pragma unroll
    for (int kst = 0; kst < 4; ++kst) {
      const int byte = (kst * 32 + g16 * 8) * 2;
      f16x8 av = *(f16x8*)swp(Vt, jt * 16 + l15, byte);
      f16x8 b0 = *(f16x8*)swp(Kt, it0 * 16 + l15, byte);
      a0 = __builtin_amdgcn_mfma_f32_16x16x32_f16(av, b0, a0, 0, 0, 0);
    }
    #pragma unroll
    for (int reg = 0; reg < 4; ++reg)
      UTb[(size_t)(jt * 16 + g16 * 4 + reg) * DHD + it0 * 16 + l15] = (_Float16)a0[reg];
  }
}

// ---------------------------------------------------------------------------
// Kernel 4: prefix combine, batched loads (validated r9/r10).
// ---------------------------------------------------------------------------
__global__ __launch_bounds__(256) void cprefix_kernel(const float* __restrict__ c0,
                                                      float* __restrict__ ws,
                                                      float* __restrict__ out) {
  const int bh = blockIdx.x >> 6;
  const int elem = ((blockIdx.x & 63) << 8) + threadIdx.x;  // j*128+i
  const int j = elem >> 7, i = elem & 127;
  const float* sc = ws + OFF_SC + bh * 80;
  float c0v = c0[(size_t)bh * 16384 + i * 128 + j];
  _Float16* Ub = (_Float16*)(ws + OFF_U) + (size_t)bh * NC * 16384 + elem;
  float uv[16];
  #pragma unroll
  for (int g = 0; g < NC; ++g) uv[g] = (float)Ub[(size_t)g * 16384];
  float P = 0.f;
  _Float16 cin[16];
  #pragma unroll
  for (int g = 0; g < NC; ++g) {
    cin[g] = (_Float16)(sc[g] * P + sc[20 + g] * c0v);
    P = sc[40 + g] * P + sc[60 + g] * uv[g];
  }
  #pragma unroll
  for (int g = 0; g < NC; ++g) Ub[(size_t)g * 16384] = cin[g];
  out[OUT_C + (size_t)bh * 16384 + i * 128 + j] = sc[16] * P + sc[36] * c0v;
}

__global__ __launch_bounds__(128) void nprefix_kernel(const float* __restrict__ n0,
                                                      float* __restrict__ ws,
                                                      float* __restrict__ out) {
  const int bh = blockIdx.x;
  const int i = threadIdx.x;
  const float* sc = ws + OFF_SC + bh * 80;
  float n0v = n0[bh * DHD + i];
  const float* Ub = ws + OFF_UN + (size_t)bh * NC * DHD + i;
  float* Nb = ws + OFF_NIN + (size_t)bh * NC * DHD + i;
  float uv[16];
  #pragma unroll
  for (int g = 0; g < NC; ++g) uv[g] = Ub[g * DHD];
  float P = 0.f;
  float nin[16];
  #pragma unroll
  for (int g = 0; g < NC; ++g) {
    nin[g] = sc[g] * P + sc[20 + g] * n0v;
    P = sc[40 + g] * P + sc[60 + g] * uv[g];
  }
  #pragma unroll
  for (int g = 0; g < NC; ++g) Nb[g * DHD] = nin[g];
  out[OUT_N + bh * DHD + i] = sc[16] * P + sc[36] * n0v;
}

// ---------------------------------------------------------------------------
// Kernel 5 (v8): r10 math, s-half split with XCD-PAIRED block mapping.
// Grid 1024 x 256 thr; half=(bid>>3)&1, pair=((bid>>4)<<3)|(bid&7) so the two
// halves of a (bh,g) share bid%8 (same XCD) and are dispatch-adjacent.
// Wave = s-tile half*4+wid; per-wave work identical to r10.
// ---------------------------------------------------------------------------
__global__ __launch_bounds__(256, 8) void intra_kernel(
    const float* __restrict__ q, const _Float16* __restrict__ kh,
    const float* __restrict__ lnw, float* __restrict__ ws, float* __restrict__ out) {
  const int tid = threadIdx.x;
  const int wid = tid >> 6;          // 0..3
  const int lane = tid & 63;
  const int g16 = lane >> 4;
  const int l15 = lane & 15;
  const int bid = blockIdx.x;
  const int half = (bid >> 3) & 1;
  const int p = ((bid >> 4) << 3) | (bid & 7);   // 0..511
  const int g = p & 15;
  const int bh = p >> 4;
  const int b = bh >> 3, hh = bh & 7;
  const int t0 = g * CL;
  const int st = half * 4 + wid;
  const int stmax = st | 1;
  const int srow = st * 16 + l15;

  const size_t headoff = (size_t)b * SS * DD + (size_t)hh * SS * DHD;
  const float* qb = q + headoff;
  const _Float16* khb = kh + headoff;
  const _Float16* CinT = (const _Float16*)(ws + OFF_U) + (size_t)(bh * NC + g) * 16384;
  const _Float16* VTb  = (const _Float16*)(ws + OFF_VT) + (size_t)(bh * NC + g) * 16384;
  const float* ninb = ws + OFF_NIN + (size_t)(bh * NC + g) * DHD;
  const float* Gb   = ws + OFF_G + (size_t)bh * SS + t0;

  const float m_in = ws[OFF_MIN + bh * NC + g];
  const float Rv_l = ws[OFF_RM + (size_t)bh * SS + t0 + srow];
  const float Bs_l = ws[OFF_B  + (size_t)bh * SS + t0 + srow];
  const float Ms_l = fmaxf(m_in, Rv_l);
  const float al_l = __expf(m_in - Ms_l);

  // ---- Q fragments + qn2 (loads batched) ----
  f16x8 qf[4];
  float qn2 = 0.f;
  {
    const float* qrow = qb + (size_t)(t0 + srow) * DHD + g16 * 8;
    float4 a[4], c[4];
    #pragma unroll
    for (int kst = 0; kst < 4; ++kst) {
      a[kst] = *(const float4*)(qrow + kst * 32);
      c[kst] = *(const float4*)(qrow + kst * 32 + 4);
    }
    float4 n0v[4], n1v[4];
    #pragma unroll
    for (int kst = 0; kst < 4; ++kst) {
      n0v[kst] = *(const float4*)(ninb + kst * 32 + g16 * 8);
      n1v[kst] = *(const float4*)(ninb + kst * 32 + g16 * 8 + 4);
    }
    #pragma unroll
    for (int kst = 0; kst < 4; ++kst) {
      qf[kst] = mkfrag(a[kst], c[kst]);
      qn2 += a[kst].x * n0v[kst].x + a[kst].y * n0v[kst].y
           + a[kst].z * n0v[kst].z + a[kst].w * n0v[kst].w
           + c[kst].x * n1v[kst].x + c[kst].y * n1v[kst].y
           + c[kst].z * n1v[kst].z + c[kst].w * n1v[kst].w;
    }
    qn2 += __shfl_xor(qn2, 16); qn2 += __shfl_xor(qn2, 32);
  }

  // ---- QC: acc = Q @ Cin; B-frags batched 8-wide (2 jt x 4 kst) ----
  f32x4 acc[8];
  #pragma unroll
  for (int jtp = 0; jtp < 4; ++jtp) {
    f16x8 bfr[8];
    #pragma unroll
    for (int jj = 0; jj < 2; ++jj)
      #pragma unroll
      for (int kst = 0; kst < 4; ++kst)
        bfr[jj * 4 + kst] = *(const f16x8*)(CinT +
            (size_t)((jtp * 2 + jj) * 16 + l15) * DHD + kst * 32 + g16 * 8);
    #pragma unroll
    for (int jj = 0; jj < 2; ++jj) {
      f32x4 a0 = {0.f, 0.f, 0.f, 0.f};
      #pragma unroll
      for (int kst = 0; kst < 4; ++kst)
        a0 = __builtin_amdgcn_mfma_f32_16x16x32_f16(qf[kst], bfr[jj * 4 + kst], a0, 0, 0, 0);
      acc[jtp * 2 + jj] = a0;
    }
  }
  {
    float av[4];
    #pragma unroll
    for (int reg = 0; reg < 4; ++reg) av[reg] = __shfl(al_l, g16 * 4 + reg);
    #pragma unroll
    for (int jt = 0; jt < 8; ++jt) {
      acc[jt][0] *= av[0]; acc[jt][1] *= av[1];
      acc[jt][2] *= av[2]; acc[jt][3] *= av[3];
    }
  }

  // ---- S-phase: rt pairs, 8 K-frag loads batched per pair ----
  unsigned pk[8][2];
  float qns = 0.f;
  #pragma unroll
  for (int rtb = 0; rtb < 4; ++rtb) {
    const int rt0 = 2 * rtb;
    if (rt0 <= stmax) {
      const _Float16* kr0 = khb + (size_t)(t0 + rt0 * 16 + l15) * DHD + g16 * 8;
      f16x8 kf[8];
      #pragma unroll
      for (int kst = 0; kst < 4; ++kst) {
        kf[kst]     = *(const f16x8*)(kr0 + kst * 32);
        kf[4 + kst] = *(const f16x8*)(kr0 + 16 * DHD + kst * 32);
      }
      float4 Gq0 = *(const float4*)(Gb + rt0 * 16 + g16 * 4);
      float4 Gq1 = *(const float4*)(Gb + (rt0 + 1) * 16 + g16 * 4);
      f32x4 sa0 = {0.f, 0.f, 0.f, 0.f}, sa1 = {0.f, 0.f, 0.f, 0.f};
      #pragma unroll
      for (int kst = 0; kst < 4; ++kst) {
        sa0 = __builtin_amdgcn_mfma_f32_16x16x32_f16(kf[kst], qf[kst], sa0, 0, 0, 0);
        sa1 = __builtin_amdgcn_mfma_f32_16x16x32_f16(kf[4 + kst], qf[kst], sa1, 0, 0, 0);
      }
      const float* G0 = (const float*)&Gq0;
      const float* G1 = (const float*)&Gq1;
      float vr0[4], vr1[4];
      #pragma unroll
      for (int rr = 0; rr < 4; ++rr) {
        const int r0i = rt0 * 16 + g16 * 4 + rr;
        const int r1i = r0i + 16;
        float w0 = (r0i <= srow) ? __expf(G0[rr] - Ms_l) * SCALE : 0.f;
        float w1 = (r1i <= srow) ? __expf(G1[rr] - Ms_l) * SCALE : 0.f;
        vr0[rr] = sa0[rr] * w0;
        vr1[rr] = sa1[rr] * w1;
      }
      qns += vr0[0] + vr0[1] + vr0[2] + vr0[3] + vr1[0] + vr1[1] + vr1[2] + vr1[3];
      pk[rt0][0]     = pk2h(vr0[0], vr0[1]);
      pk[rt0][1]     = pk2h(vr0[2], vr0[3]);
      pk[rt0 + 1][0] = pk2h(vr1[0], vr1[1]);
      pk[rt0 + 1][1] = pk2h(vr1[2], vr1[3]);
    }
  }
  qns += __shfl_xor(qns, 16); qns += __shfl_xor(qns, 32);
  const float pfull = qns + al_l * qn2;

  // ---- PV: per kst, 8 V-frag loads batched; A-frags via shfl ----
  const int kmax = (stmax + 1) >> 1;
  const int srcb = ((g16 & 1) << 5) + l15;
  const bool upper = g16 >= 2;
  #pragma unroll
  for (int kst = 0; kst < 4; ++kst) {
    if (kst < kmax) {
      f16x8 vf[8];
      #pragma unroll
      for (int jt = 0; jt < 8; ++jt)
        vf[jt] = *(const f16x8*)(VTb + (size_t)(jt * 16 + l15) * DHD + kst * 32 + g16 * 8);
      unsigned l0 = __shfl(pk[2 * kst][0], srcb);
      unsigned l1 = __shfl(pk[2 * kst][1], srcb);
      unsigned l2 = __shfl(pk[2 * kst][0], srcb + 16);
      unsigned l3 = __shfl(pk[2 * kst][1], srcb + 16);
      unsigned h0 = __shfl(pk[2 * kst + 1][0], srcb);
      unsigned h1 = __shfl(pk[2 * kst + 1][1], srcb);
      unsigned h2 = __shfl(pk[2 * kst + 1][0], srcb + 16);
      unsigned h3 = __shfl(pk[2 * kst + 1][1], srcb + 16);
      union { unsigned u[4]; f16x8 h; } pa;
      pa.u[0] = upper ? h0 : l0;
      pa.u[1] = upper ? h1 : l1;
      pa.u[2] = upper ? h2 : l2;
      pa.u[3] = upper ? h3 : l3;
      #pragma unroll
      for (int jt = 0; jt < 8; ++jt)
        acc[jt] = __builtin_amdgcn_mfma_f32_16x16x32_f16(pa.h, vf[jt], acc[jt], 0, 0, 0);
    }
  }

  // ---- epilogue: denom, LayerNorm, store ----
  const float* lw = lnw + hh * DHD;
  float lwv[8];
  #pragma unroll
  for (int jt = 0; jt < 8; ++jt) lwv[jt] = lw[jt * 16 + l15];

  const int s0 = st * 16 + g16 * 4;
  #pragma unroll
  for (int reg = 0; reg < 4; ++reg) {
    float qn_r = __shfl(pfull, g16 * 4 + reg);
    float B_r  = __shfl(Bs_l,  g16 * 4 + reg);
    float M_r  = __shfl(Ms_l,  g16 * 4 + reg);
    float den = fmaxf(fabsf(qn_r), __expf(-(B_r + M_r))) + 1e-6f;
    float inv = 1.0f / den;
    float mp = 0.f, sp = 0.f;
    float hv[8];
    #pragma unroll
    for (int jt = 0; jt < 8; ++jt) {
      float h = acc[jt][reg] * inv;
      hv[jt] = h;
      mp += h; sp += h * h;
    }
    mp += __shfl_xor(mp, 1); sp += __shfl_xor(sp, 1);
    mp += __shfl_xor(mp, 2); sp += __shfl_xor(sp, 2);
    mp += __shfl_xor(mp, 4); sp += __shfl_xor(sp, 4);
    mp += __shfl_xor(mp, 8); sp += __shfl_xor(sp, 8);
    float mu = mp * (1.f / 128.f);
    float var = fmaxf(sp * (1.f / 128.f) - mu * mu, 0.f);
    float rstd = rsqrtf(var + 1e-6f);
    float* orow = out + (size_t)(b * SS + t0 + s0 + reg) * DD + hh * DHD;
    #pragma unroll
    for (int jt = 0; jt < 8; ++jt)
      orow[jt * 16 + l15] = (hv[jt] - mu) * rstd * lwv[jt];
  }
}

extern "C" void kernel_launch(void* const* d_in, const int* in_sizes, int n_in,
                              void* d_out, int out_size, void* d_ws, size_t ws_size,
                              hipStream_t stream) {
  const float* q   = (const float*)d_in[0];
  const float* k   = (const float*)d_in[1];
  const float* v   = (const float*)d_in[2];
  const float* c0  = (const float*)d_in[3];
  const float* n0  = (const float*)d_in[4];
  const float* m0  = (const float*)d_in[5];
  const float* Wi  = (const float*)d_in[6];
  const float* bi  = (const float*)d_in[7];
  const float* Wf  = (const float*)d_in[8];
  const float* bf  = (const float*)d_in[9];
  const float* lnw = (const float*)d_in[10];
  float* out = (float*)d_out;
  float* ws  = (float*)d_ws;

  _Float16* WT = (_Float16*)(ws + OFF_U);   // dead until u_kernel overwrites
  _Float16* kh = (_Float16*)(ws + OFF_KH);

  wtrans_kernel<<<12, 256, 0, stream>>>(Wi, Wf, WT);
  gates_kernel<<<BB * SS / 16 * 2, 512, 0, stream>>>(q, k, v, WT, ws, kh);
  prep1_kernel<<<BB * NHD * NC, 128, 0, stream>>>(ws, bi, bf);
  prep2_kernel<<<BB * NHD, 64, 0, stream>>>(ws, m0, out);
  u_kernel<<<BB * NHD * NC, 512, 65536, stream>>>(k, v, ws);
  cprefix_kernel<<<BB * NHD * 64, 256, 0, stream>>>(c0, ws, out);
  nprefix_kernel<<<BB * NHD, 128, 0, stream>>>(n0, ws, out);
  intra_kernel<<<BB * NHD * NC * 2, 256, 0, stream>>>(q, kh, lnw, ws, out);
}

// Round 17
// 112.985 us; speedup vs baseline: 1.2616x; 1.2616x over previous
//
#include <hip/hip_runtime.h>
#include <math.h>

#define BB 4
#define SS 2048
#define DD 1024
#define NHD 8
#define DHD 128
#define NC 16
#define CL 128
#define SCALE 0.08838834764831845f

// workspace offsets (in floats)
#define OFF_IG   0
#define OFF_LF   65536
#define OFF_B    131072
#define OFF_G    196608
#define OFF_E    262144
#define OFF_RM   327680
#define OFF_MIN  393216
#define OFF_SC   393728
#define OFF_UN   396288
#define OFF_NIN  461824
#define OFF_U    527360      // f16: WT (gates) then U^T/Cin^T
#define OFF_KH   4721664     // f16 mirror of k
#define OFF_VT   8915968     // f16 V^T per (bh,g)
#define OFF_IG2  13110272    // gates K-half-1 partial (raw)
#define OFF_LF2  13175808    // gates K-half-1 partial (raw)
// out offsets (floats)
#define OUT_C  8388608
#define OUT_N  8912896
#define OUT_M  8916992

typedef __attribute__((ext_vector_type(8))) _Float16 f16x8;
typedef __attribute__((ext_vector_type(4))) float f32x4;

__device__ __forceinline__ unsigned pk2h(float a, float b) {
  union { _Float16 h[2]; unsigned u; } f;
  f.h[0] = (_Float16)a; f.h[1] = (_Float16)b;
  return f.u;
}
__device__ __forceinline__ f16x8 mkfrag(float4 a, float4 c) {
  f16x8 f;
  f[0] = (_Float16)a.x; f[1] = (_Float16)a.y; f[2] = (_Float16)a.z; f[3] = (_Float16)a.w;
  f[4] = (_Float16)c.x; f[5] = (_Float16)c.y; f[6] = (_Float16)c.z; f[7] = (_Float16)c.w;
  return f;
}
// 256B rows, XOR-swizzle byte bits 4..6 with row&7
__device__ __forceinline__ char* swp(char* base, int row, int byte) {
  return base + (((row << 8) + byte) ^ ((row & 7) << 4));
}

// ---------------------------------------------------------------------------
// Kernel 0: transpose Wi|Wf -> WT f16 [16][3072] (validated).
// ---------------------------------------------------------------------------
__global__ __launch_bounds__(256) void wtrans_kernel(const float* __restrict__ Wi,
                                                     const float* __restrict__ Wf,
                                                     _Float16* __restrict__ WT) {
  const int kk = blockIdx.x * 256 + threadIdx.x;   // 0..3071
  float4 wa = *(const float4*)(Wi + (size_t)kk * 8);
  float4 wb = *(const float4*)(Wi + (size_t)kk * 8 + 4);
  float4 fa = *(const float4*)(Wf + (size_t)kk * 8);
  float4 fb = *(const float4*)(Wf + (size_t)kk * 8 + 4);
  WT[0 * 3072 + kk]  = (_Float16)wa.x; WT[1 * 3072 + kk]  = (_Float16)wa.y;
  WT[2 * 3072 + kk]  = (_Float16)wa.z; WT[3 * 3072 + kk]  = (_Float16)wa.w;
  WT[4 * 3072 + kk]  = (_Float16)wb.x; WT[5 * 3072 + kk]  = (_Float16)wb.y;
  WT[6 * 3072 + kk]  = (_Float16)wb.z; WT[7 * 3072 + kk]  = (_Float16)wb.w;
  WT[8 * 3072 + kk]  = (_Float16)fa.x; WT[9 * 3072 + kk]  = (_Float16)fa.y;
  WT[10 * 3072 + kk] = (_Float16)fa.z; WT[11 * 3072 + kk] = (_Float16)fa.w;
  WT[12 * 3072 + kk] = (_Float16)fb.x; WT[13 * 3072 + kk] = (_Float16)fb.y;
  WT[14 * 3072 + kk] = (_Float16)fb.z; WT[15 * 3072 + kk] = (_Float16)fb.w;
}

// ---------------------------------------------------------------------------
// Kernel 1 (v5): gates MFMA, K-SPLIT over 2 blocks (validated r15).
// ---------------------------------------------------------------------------
__global__ __launch_bounds__(512) void gates_kernel(
    const float* __restrict__ q, const float* __restrict__ k, const float* __restrict__ v,
    const _Float16* __restrict__ WT, float* __restrict__ ws,
    _Float16* __restrict__ kh) {
  __shared__ float red[8][256];
  const int tid = threadIdx.x, wid = tid >> 6, lane = tid & 63;
  const int g16 = lane >> 4, l15 = lane & 15;
  const int khalf = blockIdx.x & 1;
  const int rb = blockIdx.x >> 1;
  const int g0 = rb * 16;
  const int b = g0 >> 11, t0 = g0 & (SS - 1);

  const size_t rowoff = (size_t)b * SS * DD + (size_t)(t0 + l15) * DD;
  const float* qr = q + rowoff;
  const float* kr = k + rowoff;
  const float* vr = v + rowoff;

  f32x4 acc = {0.f, 0.f, 0.f, 0.f};
  const int ks0 = khalf * 48 + wid * 6;
  #pragma unroll
  for (int grp = 0; grp < 3; ++grp) {
    const int s0 = ks0 + grp * 2;
    const int seg = s0 >> 5;
    const float* base = (seg == 0) ? qr : (seg == 1) ? kr : vr;
    const float* Ab = base + (s0 & 31) * 32 + g16 * 8;
    const _Float16* Bb = WT + l15 * 3072 + s0 * 32 + g16 * 8;
    float4 a[2], c[2]; f16x8 bfr[2];
    #pragma unroll
    for (int j = 0; j < 2; ++j) {
      a[j]   = *(const float4*)(Ab + j * 32);
      c[j]   = *(const float4*)(Ab + j * 32 + 4);
      bfr[j] = *(const f16x8*)(Bb + j * 32);
    }
    if (seg == 1) {
      const int coff = (s0 & 31) * 32 + g16 * 8;
      #pragma unroll
      for (int j = 0; j < 2; ++j)
        *(f16x8*)(kh + rowoff + coff + j * 32) = mkfrag(a[j], c[j]);
    }
    #pragma unroll
    for (int j = 0; j < 2; ++j)
      acc = __builtin_amdgcn_mfma_f32_16x16x32_f16(mkfrag(a[j], c[j]), bfr[j], acc, 0, 0, 0);
  }
  #pragma unroll
  for (int r = 0; r < 4; ++r) red[wid][(g16 * 4 + r) * 16 + l15] = acc[r];
  __syncthreads();

  if (tid < 256) {
    float s = 0.f;
    #pragma unroll
    for (int w = 0; w < 8; ++w) s += red[w][tid];
    const int row = tid >> 4, gate = tid & 15;
    const int t = t0 + row;
    float* igb = ws + (khalf ? OFF_IG2 : OFF_IG);
    float* lfb = ws + (khalf ? OFF_LF2 : OFF_LF);
    if (gate < 8) igb[(size_t)(b * NHD + gate) * SS + t] = s;
    else          lfb[(size_t)(b * NHD + gate - 8) * SS + t] = s;
  }
}

// ---------------------------------------------------------------------------
// Kernel 2a: per-chunk scans + gate partial sum + bias/lsig (validated r15).
// ---------------------------------------------------------------------------
__global__ __launch_bounds__(128) void prep1_kernel(float* __restrict__ ws,
                                                    const float* __restrict__ bi,
                                                    const float* __restrict__ bfb) {
  const int g  = blockIdx.x & 15;
  const int bh = blockIdx.x >> 4;
  const int hh = bh & 7;
  const int s  = threadIdx.x;
  __shared__ float sh[128];
  __shared__ float bc1;
  const int t = g * CL + s;
  const size_t off = (size_t)bh * SS + t;
  float ft  = ws[OFF_LF + off] + ws[OFF_LF2 + off] + bfb[hh];
  float lfv = fminf(ft, 0.f) - log1pf(expf(-fabsf(ft)));
  float iv  = ws[OFF_IG + off] + ws[OFF_IG2 + off] + bi[hh];
  float v = lfv;
  sh[s] = v; __syncthreads();
  for (int off2 = 1; off2 < 128; off2 <<= 1) {
    float tv = (s >= off2) ? sh[s - off2] : 0.f;
    __syncthreads();
    v += tv; sh[s] = v; __syncthreads();
  }
  float Bv = v;
  float Gv = iv - Bv;
  v = Gv; sh[s] = v; __syncthreads();
  for (int off2 = 1; off2 < 128; off2 <<= 1) {
    float tv = (s >= off2) ? sh[s - off2] : -3.0e38f;
    __syncthreads();
    v = fmaxf(v, tv); sh[s] = v; __syncthreads();
  }
  float Rv = v;
  if (s == 127) bc1 = Rv;
  __syncthreads();
  float mxG = bc1;
  ws[OFF_B  + off] = Bv;
  ws[OFF_G  + off] = Gv;
  ws[OFF_RM + off] = Rv;
  ws[OFF_E  + off] = expf(Gv - mxG);
}

// Kernel 2b: per-bh cross-chunk scalar chain (validated r9/r15).
__global__ __launch_bounds__(64) void prep2_kernel(float* __restrict__ ws,
                                                   const float* __restrict__ m0,
                                                   float* __restrict__ out) {
  const int bh = blockIdx.x;
  if (threadIdx.x != 0) return;
  const float m0v = m0[bh];
  float m_run = m0v, LFtot = 0.f;
  float mina[NC], mxga[NC], lfsa[NC];
  #pragma unroll
  for (int g = 0; g < NC; ++g) {
    float Bend = ws[OFF_B  + (size_t)bh * SS + g * CL + 127];
    float mxG  = ws[OFF_RM + (size_t)bh * SS + g * CL + 127];
    ws[OFF_MIN + bh * NC + g] = m_run;
    mina[g] = m_run; mxga[g] = mxG; lfsa[g] = LFtot;
    m_run = Bend + fmaxf(m_run, mxG);
    LFtot += Bend;
  }
  out[OUT_M + bh] = m_run;
  float* sc = ws + OFF_SC + bh * 80;
  float S = -3.0e38f;
  #pragma unroll
  for (int g = 0; g < NC; ++g) {
    float r_g = lfsa[g] - mina[g];
    sc[g]      = expf(S + r_g);
    sc[20 + g] = expf(m0v + lfsa[g] - mina[g]);
    float s_g = mxga[g] - lfsa[g];
    float Sn = fmaxf(S, s_g);
    sc[40 + g] = expf(S - Sn);
    sc[60 + g] = expf(s_g - Sn);
    S = Sn;
  }
  sc[16] = expf(S + LFtot - m_run);
  sc[36] = expf(m0v + LFtot - m_run);
}

// ---------------------------------------------------------------------------
// Kernel 3 (v2): MFMA U^T + Un + V^T dump, 512 thr / 8 waves (validated r15).
// ---------------------------------------------------------------------------
__global__ __launch_bounds__(512) void u_kernel(const float* __restrict__ k,
                                                const float* __restrict__ v,
                                                float* __restrict__ ws) {
  extern __shared__ char smem[];
  char* Kt = smem;
  char* Vt = smem + 32768;

  const int tid = threadIdx.x;
  const int wid = tid >> 6;          // 0..7
  const int lane = tid & 63;
  const int g16 = lane >> 4;
  const int l15 = lane & 15;
  const int g  = blockIdx.x & 15;
  const int bh = blockIdx.x >> 4;
  const int b = bh >> 3, hh = bh & 7;
  const size_t headoff = (size_t)b * SS * DD + (size_t)hh * SS * DHD;
  const float* kb = k + headoff + (size_t)g * CL * DHD;
  const float* vb = v + headoff + (size_t)g * CL * DHD;
  const float* E  = ws + OFF_E + (size_t)bh * SS + g * CL;

  #pragma unroll 4
  for (int it = 0; it < 8; ++it) {
    const int idx = (it << 9) + tid;
    const int c  = idx & 127;
    const int r0 = (idx >> 7) << 2;
    float e0 = E[r0] * SCALE, e1 = E[r0 + 1] * SCALE,
          e2 = E[r0 + 2] * SCALE, e3 = E[r0 + 3] * SCALE;
    float a0 = kb[(size_t)r0 * DHD + c] * e0;
    float a1 = kb[(size_t)(r0 + 1) * DHD + c] * e1;
    float a2 = kb[(size_t)(r0 + 2) * DHD + c] * e2;
    float a3 = kb[(size_t)(r0 + 3) * DHD + c] * e3;
    *(uint2*)swp(Kt, c, r0 * 2) = make_uint2(pk2h(a0, a1), pk2h(a2, a3));
    float b0 = vb[(size_t)r0 * DHD + c];
    float b1 = vb[(size_t)(r0 + 1) * DHD + c];
    float b2 = vb[(size_t)(r0 + 2) * DHD + c];
    float b3 = vb[(size_t)(r0 + 3) * DHD + c];
    *(uint2*)swp(Vt, c, r0 * 2) = make_uint2(pk2h(b0, b1), pk2h(b2, b3));
  }
  __syncthreads();

  _Float16* VTg = (_Float16*)(ws + OFF_VT) + (size_t)(bh * NC + g) * 16384;
  #pragma unroll
  for (int it2 = 0; it2 < 4; ++it2) {
    const int ci = (it2 << 9) + tid;
    const int j = ci >> 4, rp = ci & 15;
    f16x8 x = *(f16x8*)swp(Vt, j, rp * 16);
    *(f16x8*)(VTg + j * 128 + rp * 8) = x;
  }

  if (tid < 128) {
    float s = 0.f;
    #pragma unroll
    for (int r8 = 0; r8 < 16; ++r8) {
      f16x8 x = *(f16x8*)swp(Kt, tid, r8 * 16);
      s += (float)x[0] + (float)x[1] + (float)x[2] + (float)x[3]
         + (float)x[4] + (float)x[5] + (float)x[6] + (float)x[7];
    }
    ws[OFF_UN + (size_t)(bh * NC + g) * DHD + tid] = s;
  }

  _Float16* UTb = (_Float16*)(ws + OFF_U) + (size_t)(bh * NC + g) * 16384;
  const int it0 = wid;
  #pragma unroll 1
  for (int jt = 0; jt < 8; ++jt) {
    f32x4 a0 = {0.f, 0.f, 0.f, 0.f};
    #pragma unroll
    for (int kst = 0; kst < 4; ++kst) {
      const int byte = (kst * 32 + g16 * 8) * 2;
      f16x8 av = *(f16x8*)swp(Vt, jt * 16 + l15, byte);
      f16x8 b0 = *(f16x8*)swp(Kt, it0 * 16 + l15, byte);
      a0 = __builtin_amdgcn_mfma_f32_16x16x32_f16(av, b0, a0, 0, 0, 0);
    }
    #pragma unroll
    for (int reg = 0; reg < 4; ++reg)
      UTb[(size_t)(jt * 16 + g16 * 4 + reg) * DHD + it0 * 16 + l15] = (_Float16)a0[reg];
  }
}

// ---------------------------------------------------------------------------
// Kernel 4: prefix combine, batched loads (validated r9/r10).
// ---------------------------------------------------------------------------
__global__ __launch_bounds__(256) void cprefix_kernel(const float* __restrict__ c0,
                                                      float* __restrict__ ws,
                                                      float* __restrict__ out) {
  const int bh = blockIdx.x >> 6;
  const int elem = ((blockIdx.x & 63) << 8) + threadIdx.x;  // j*128+i
  const int j = elem >> 7, i = elem & 127;
  const float* sc = ws + OFF_SC + bh * 80;
  float c0v = c0[(size_t)bh * 16384 + i * 128 + j];
  _Float16* Ub = (_Float16*)(ws + OFF_U) + (size_t)bh * NC * 16384 + elem;
  float uv[16];
  #pragma unroll
  for (int g = 0; g < NC; ++g) uv[g] = (float)Ub[(size_t)g * 16384];
  float P = 0.f;
  _Float16 cin[16];
  #pragma unroll
  for (int g = 0; g < NC; ++g) {
    cin[g] = (_Float16)(sc[g] * P + sc[20 + g] * c0v);
    P = sc[40 + g] * P + sc[60 + g] * uv[g];
  }
  #pragma unroll
  for (int g = 0; g < NC; ++g) Ub[(size_t)g * 16384] = cin[g];
  out[OUT_C + (size_t)bh * 16384 + i * 128 + j] = sc[16] * P + sc[36] * c0v;
}

__global__ __launch_bounds__(128) void nprefix_kernel(const float* __restrict__ n0,
                                                      float* __restrict__ ws,
                                                      float* __restrict__ out) {
  const int bh = blockIdx.x;
  const int i = threadIdx.x;
  const float* sc = ws + OFF_SC + bh * 80;
  float n0v = n0[bh * DHD + i];
  const float* Ub = ws + OFF_UN + (size_t)bh * NC * DHD + i;
  float* Nb = ws + OFF_NIN + (size_t)bh * NC * DHD + i;
  float uv[16];
  #pragma unroll
  for (int g = 0; g < NC; ++g) uv[g] = Ub[g * DHD];
  float P = 0.f;
  float nin[16];
  #pragma unroll
  for (int g = 0; g < NC; ++g) {
    nin[g] = sc[g] * P + sc[20 + g] * n0v;
    P = sc[40 + g] * P + sc[60 + g] * uv[g];
  }
  #pragma unroll
  for (int g = 0; g < NC; ++g) Nb[g * DHD] = nin[g];
  out[OUT_N + bh * DHD + i] = sc[16] * P + sc[36] * n0v;
}

// ---------------------------------------------------------------------------
// Kernel 5 (r10/r15 exact, best measured 46.2us): 512 blk x 512 thr,
// wave = s-tile, zero LDS/barriers, 8-wide load batching.
// ---------------------------------------------------------------------------
__global__ __launch_bounds__(512, 4) void intra_kernel(
    const float* __restrict__ q, const _Float16* __restrict__ kh,
    const float* __restrict__ lnw, float* __restrict__ ws, float* __restrict__ out) {
  const int tid = threadIdx.x;
  const int wid = tid >> 6;          // s-tile 0..7
  const int lane = tid & 63;
  const int g16 = lane >> 4;
  const int l15 = lane & 15;
  const int g = blockIdx.x & 15;
  const int bh = blockIdx.x >> 4;
  const int b = bh >> 3, hh = bh & 7;
  const int t0 = g * CL;
  const int st = wid;
  const int stmax = st | 1;
  const int srow = st * 16 + l15;

  const size_t headoff = (size_t)b * SS * DD + (size_t)hh * SS * DHD;
  const float* qb = q + headoff;
  const _Float16* khb = kh + headoff;
  const _Float16* CinT = (const _Float16*)(ws + OFF_U) + (size_t)(bh * NC + g) * 16384;
  const _Float16* VTb  = (const _Float16*)(ws + OFF_VT) + (size_t)(bh * NC + g) * 16384;
  const float* ninb = ws + OFF_NIN + (size_t)(bh * NC + g) * DHD;
  const float* Gb   = ws + OFF_G + (size_t)bh * SS + t0;

  const float m_in = ws[OFF_MIN + bh * NC + g];
  const float Rv_l = ws[OFF_RM + (size_t)bh * SS + t0 + srow];
  const float Bs_l = ws[OFF_B  + (size_t)bh * SS + t0 + srow];
  const float Ms_l = fmaxf(m_in, Rv_l);
  const float al_l = __expf(m_in - Ms_l);

  // ---- Q fragments + qn2 (loads batched) ----
  f16x8 qf[4];
  float qn2 = 0.f;
  {
    const float* qrow = qb + (size_t)(t0 + srow) * DHD + g16 * 8;
    float4 a[4], c[4];
    #pragma unroll
    for (int kst = 0; kst < 4; ++kst) {
      a[kst] = *(const float4*)(qrow + kst * 32);
      c[kst] = *(const float4*)(qrow + kst * 32 + 4);
    }
    float4 n0v[4], n1v[4];
    #pragma unroll
    for (int kst = 0; kst < 4; ++kst) {
      n0v[kst] = *(const float4*)(ninb + kst * 32 + g16 * 8);
      n1v[kst] = *(const float4*)(ninb + kst * 32 + g16 * 8 + 4);
    }
    #pragma unroll
    for (int kst = 0; kst < 4; ++kst) {
      qf[kst] = mkfrag(a[kst], c[kst]);
      qn2 += a[kst].x * n0v[kst].x + a[kst].y * n0v[kst].y
           + a[kst].z * n0v[kst].z + a[kst].w * n0v[kst].w
           + c[kst].x * n1v[kst].x + c[kst].y * n1v[kst].y
           + c[kst].z * n1v[kst].z + c[kst].w * n1v[kst].w;
    }
    qn2 += __shfl_xor(qn2, 16); qn2 += __shfl_xor(qn2, 32);
  }

  // ---- QC: acc = Q @ Cin; B-frags batched 8-wide (2 jt x 4 kst) ----
  f32x4 acc[8];
  #pragma unroll
  for (int jtp = 0; jtp < 4; ++jtp) {
    f16x8 bfr[8];
    #pragma unroll
    for (int jj = 0; jj < 2; ++jj)
      #pragma unroll
      for (int kst = 0; kst < 4; ++kst)
        bfr[jj * 4 + kst] = *(const f16x8*)(CinT +
            (size_t)((jtp * 2 + jj) * 16 + l15) * DHD + kst * 32 + g16 * 8);
    #pragma unroll
    for (int jj = 0; jj < 2; ++jj) {
      f32x4 a0 = {0.f, 0.f, 0.f, 0.f};
      #pragma unroll
      for (int kst = 0; kst < 4; ++kst)
        a0 = __builtin_amdgcn_mfma_f32_16x16x32_f16(qf[kst], bfr[jj * 4 + kst], a0, 0, 0, 0);
      acc[jtp * 2 + jj] = a0;
    }
  }
  {
    float av[4];
    #pragma unroll
    for (int reg = 0; reg < 4; ++reg) av[reg] = __shfl(al_l, g16 * 4 + reg);
    #pragma unroll
    for (int jt = 0; jt < 8; ++jt) {
      acc[jt][0] *= av[0]; acc[jt][1] *= av[1];
      acc[jt][2] *= av[2]; acc[jt][3] *= av[3];
    }
  }

  // ---- S-phase: rt pairs, 8 K-frag loads batched per pair ----
  unsigned pk[8][2];
  float qns = 0.f;
  #pragma unroll
  for (int rtb = 0; rtb < 4; ++rtb) {
    const int rt0 = 2 * rtb;
    if (rt0 <= stmax) {
      const _Float16* kr0 = khb + (size_t)(t0 + rt0 * 16 + l15) * DHD + g16 * 8;
      f16x8 kf[8];
      #pragma unroll
      for (int kst = 0; kst < 4; ++kst) {
        kf[kst]     = *(const f16x8*)(kr0 + kst * 32);
        kf[4 + kst] = *(const f16x8*)(kr0 + 16 * DHD + kst * 32);
      }
      float4 Gq0 = *(const float4*)(Gb + rt0 * 16 + g16 * 4);
      float4 Gq1 = *(const float4*)(Gb + (rt0 + 1) * 16 + g16 * 4);
      f32x4 sa0 = {0.f, 0.f, 0.f, 0.f}, sa1 = {0.f, 0.f, 0.f, 0.f};
      #pragma unroll
      for (int kst = 0; kst < 4; ++kst) {
        sa0 = __builtin_amdgcn_mfma_f32_16x16x32_f16(kf[kst], qf[kst], sa0, 0, 0, 0);
        sa1 = __builtin_amdgcn_mfma_f32_16x16x32_f16(kf[4 + kst], qf[kst], sa1, 0, 0, 0);
      }
      const float* G0 = (const float*)&Gq0;
      const float* G1 = (const float*)&Gq1;
      float vr0[4], vr1[4];
      #pragma unroll
      for (int rr = 0; rr < 4; ++rr) {
        const int r0i = rt0 * 16 + g16 * 4 + rr;
        const int r1i = r0i + 16;
        float w0 = (r0i <= srow) ? __expf(G0[rr] - Ms_l) * SCALE : 0.f;
        float w1 = (r1i <= srow) ? __expf(G1[rr] - Ms_l) * SCALE : 0.f;
        vr0[rr] = sa0[rr] * w0;
        vr1[rr] = sa1[rr] * w1;
      }
      qns += vr0[0] + vr0[1] + vr0[2] + vr0[3] + vr1[0] + vr1[1] + vr1[2] + vr1[3];
      pk[rt0][0]     = pk2h(vr0[0], vr0[1]);
      pk[rt0][1]     = pk2h(vr0[2], vr0[3]);
      pk[rt0 + 1][0] = pk2h(vr1[0], vr1[1]);
      pk[rt0 + 1][1] = pk2h(vr1[2], vr1[3]);
    }
  }
  qns += __shfl_xor(qns, 16); qns += __shfl_xor(qns, 32);
  const float pfull = qns + al_l * qn2;

  // ---- PV: per kst, 8 V-frag loads batched; A-frags via shfl ----
  const int kmax = (stmax + 1) >> 1;
  const int srcb = ((g16 & 1) << 5) + l15;
  const bool upper = g16 >= 2;
  #pragma unroll
  for (int kst = 0; kst < 4; ++kst) {
    if (kst < kmax) {
      f16x8 vf[8];
      #pragma unroll
      for (int jt = 0; jt < 8; ++jt)
        vf[jt] = *(const f16x8*)(VTb + (size_t)(jt * 16 + l15) * DHD + kst * 32 + g16 * 8);
      unsigned l0 = __shfl(pk[2 * kst][0], srcb);
      unsigned l1 = __shfl(pk[2 * kst][1], srcb);
      unsigned l2 = __shfl(pk[2 * kst][0], srcb + 16);
      unsigned l3 = __shfl(pk[2 * kst][1], srcb + 16);
      unsigned h0 = __shfl(pk[2 * kst + 1][0], srcb);
      unsigned h1 = __shfl(pk[2 * kst + 1][1], srcb);
      unsigned h2 = __shfl(pk[2 * kst + 1][0], srcb + 16);
      unsigned h3 = __shfl(pk[2 * kst + 1][1], srcb + 16);
      union { unsigned u[4]; f16x8 h; } pa;
      pa.u[0] = upper ? h0 : l0;
      pa.u[1] = upper ? h1 : l1;
      pa.u[2] = upper ? h2 : l2;
      pa.u[3] = upper ? h3 : l3;
      #pragma unroll
      for (int jt = 0; jt < 8; ++jt)
        acc[jt] = __builtin_amdgcn_mfma_f32_16x16x32_f16(pa.h, vf[jt], acc[jt], 0, 0, 0);
    }
  }

  // ---- epilogue: denom, LayerNorm, store ----
  const float* lw = lnw + hh * DHD;
  float lwv[8];
  #pragma unroll
  for (int jt = 0; jt < 8; ++jt) lwv[jt] = lw[jt * 16 + l15];

  const int s0 = st * 16 + g16 * 4;
  #pragma unroll
  for (int reg = 0; reg < 4; ++reg) {
    float qn_r = __shfl(pfull, g16 * 4 + reg);
    float B_r  = __shfl(Bs_l,  g16 * 4 + reg);
    float M_r  = __shfl(Ms_l,  g16 * 4 + reg);
    float den = fmaxf(fabsf(qn_r), __expf(-(B_r + M_r))) + 1e-6f;
    float inv = 1.0f / den;
    float mp = 0.f, sp = 0.f;
    float hv[8];
    #pragma unroll
    for (int jt = 0; jt < 8; ++jt) {
      float h = acc[jt][reg] * inv;
      hv[jt] = h;
      mp += h; sp += h * h;
    }
    mp += __shfl_xor(mp, 1); sp += __shfl_xor(sp, 1);
    mp += __shfl_xor(mp, 2); sp += __shfl_xor(sp, 2);
    mp += __shfl_xor(mp, 4); sp += __shfl_xor(sp, 4);
    mp += __shfl_xor(mp, 8); sp += __shfl_xor(sp, 8);
    float mu = mp * (1.f / 128.f);
    float var = fmaxf(sp * (1.f / 128.f) - mu * mu, 0.f);
    float rstd = rsqrtf(var + 1e-6f);
    float* orow = out + (size_t)(b * SS + t0 + s0 + reg) * DD + hh * DHD;
    #pragma unroll
    for (int jt = 0; jt < 8; ++jt)
      orow[jt * 16 + l15] = (hv[jt] - mu) * rstd * lwv[jt];
  }
}

extern "C" void kernel_launch(void* const* d_in, const int* in_sizes, int n_in,
                              void* d_out, int out_size, void* d_ws, size_t ws_size,
                              hipStream_t stream) {
  const float* q   = (const float*)d_in[0];
  const float* k   = (const float*)d_in[1];
  const float* v   = (const float*)d_in[2];
  const float* c0  = (const float*)d_in[3];
  const float* n0  = (const float*)d_in[4];
  const float* m0  = (const float*)d_in[5];
  const float* Wi  = (const float*)d_in[6];
  const float* bi  = (const float*)d_in[7];
  const float* Wf  = (const float*)d_in[8];
  const float* bf  = (const float*)d_in[9];
  const float* lnw = (const float*)d_in[10];
  float* out = (float*)d_out;
  float* ws  = (float*)d_ws;

  _Float16* WT = (_Float16*)(ws + OFF_U);   // dead until u_kernel overwrites
  _Float16* kh = (_Float16*)(ws + OFF_KH);

  wtrans_kernel<<<12, 256, 0, stream>>>(Wi, Wf, WT);
  gates_kernel<<<BB * SS / 16 * 2, 512, 0, stream>>>(q, k, v, WT, ws, kh);
  prep1_kernel<<<BB * NHD * NC, 128, 0, stream>>>(ws, bi, bf);
  prep2_kernel<<<BB * NHD, 64, 0, stream>>>(ws, m0, out);
  u_kernel<<<BB * NHD * NC, 512, 65536, stream>>>(k, v, ws);
  cprefix_kernel<<<BB * NHD * 64, 256, 0, stream>>>(c0, ws, out);
  nprefix_kernel<<<BB * NHD, 128, 0, stream>>>(n0, ws, out);
  intra_kernel<<<BB * NHD * NC, 512, 0, stream>>>(q, kh, lnw, ws, out);
}